// Round 6
// baseline (693.074 us; speedup 1.0000x reference)
//
#include <hip/hip_runtime.h>

#define LB __launch_bounds__(256)

// ---------------------------------------------------------------------------
// Weight pre-transpose:
//  wc [64][256]   -> wcT [stage][c=256][o=64]          (o contiguous per c)
//  we [36][64][9] -> weT [stage][pq=4][i=64][kt=9][16] (kk padded to 16)
// ---------------------------------------------------------------------------
__global__ LB void prep_weights(
    const float* __restrict__ wcA, const float* __restrict__ wcB,
    const float* __restrict__ wcC, const float* __restrict__ wcD,
    const float* __restrict__ weA, const float* __restrict__ weB,
    const float* __restrict__ weC, const float* __restrict__ weD,
    float* __restrict__ wcT, float* __restrict__ weT)
{
    int seg = blockIdx.y;
    int t = blockIdx.x * 256 + threadIdx.x;
    if (seg < 4) {
        if (t >= 64 * 256) return;
        const float* w = (seg == 0) ? wcA : (seg == 1) ? wcB : (seg == 2) ? wcC : wcD;
        int c = t & 255, o = t >> 8;          // t = o*256 + c (coalesced read)
        wcT[seg * 16384 + c * 64 + o] = w[t];
    } else {
        if (t >= 36 * 64 * 9) return;
        const float* w = (seg == 4) ? weA : (seg == 5) ? weB : (seg == 6) ? weC : weD;
        int kt = t % 9;
        int r = t / 9;
        int i = r & 63;
        int o = r >> 6;                        // t = (o*64+i)*9+kt (coalesced read)
        int kk = o >> 2, pq = o & 3;
        weT[(seg - 4) * 36864 + ((pq * 64 + i) * 9 + kt) * 16 + kk] = w[t];
    }
}

// ---------------------------------------------------------------------------
// K1: 1x1 conv 256 -> 64.  Block = 64 px x 4 og-waves.
// MLP-deepened: c-loop in chunks of 16; all 16 x-loads issued before the
// dependent FMA phase -> 16 outstanding HBM loads per wave (was ~2).
// ---------------------------------------------------------------------------
__global__ LB void compress_k(const float* __restrict__ x, const float* __restrict__ wcT,
                              const float* __restrict__ bc, float* __restrict__ comp, int lgW)
{
    const int lgHW = 2 * lgW;
    const int HW = 1 << lgHW;
    int lane = threadIdx.x & 63;
    int og = __builtin_amdgcn_readfirstlane(threadIdx.x >> 6);   // 0..3
    int pix = blockIdx.x * 64 + lane;
    int b = pix >> lgHW;
    int hw = pix & (HW - 1);
    const float* xp = x + (((size_t)b * 256) << lgHW) + hw;
    const float* wr = wcT + og * 16;

    float acc[16];
    #pragma unroll
    for (int j = 0; j < 16; j++) acc[j] = bc[og * 16 + j];

    for (int c0 = 0; c0 < 256; c0 += 16) {
        // ---- load phase: 16 independent x loads in flight ----
        float xv[16];
        #pragma unroll
        for (int u = 0; u < 16; u++)
            xv[u] = xp[(size_t)(c0 + u) << lgHW];
        // ---- compute phase: weights are L1-resident ----
        #pragma unroll
        for (int u = 0; u < 16; u++) {
            const float* w = wr + (c0 + u) * 64;
            float4 w0 = *(const float4*)(w);
            float4 w1 = *(const float4*)(w + 4);
            float4 w2 = *(const float4*)(w + 8);
            float4 w3 = *(const float4*)(w + 12);
            float xu = xv[u];
            acc[0]  += w0.x * xu; acc[1]  += w0.y * xu; acc[2]  += w0.z * xu; acc[3]  += w0.w * xu;
            acc[4]  += w1.x * xu; acc[5]  += w1.y * xu; acc[6]  += w1.z * xu; acc[7]  += w1.w * xu;
            acc[8]  += w2.x * xu; acc[9]  += w2.y * xu; acc[10] += w2.z * xu; acc[11] += w2.w * xu;
            acc[12] += w3.x * xu; acc[13] += w3.y * xu; acc[14] += w3.z * xu; acc[15] += w3.w * xu;
        }
    }

    float* op = comp + (((size_t)b * 64 + og * 16) << lgHW) + hw;
    #pragma unroll
    for (int j = 0; j < 16; j++) op[(size_t)j << lgHW] = acc[j];
}

// ---------------------------------------------------------------------------
// K2: 3x3 conv 64 -> 36 fused pixel-shuffle + softmax.
// Block = 64 px x 4 pq-waves.  i-loop unrolled x2 with both channels' 9 taps
// loaded up front -> 18 outstanding loads.
// ---------------------------------------------------------------------------
__global__ LB void encoder_k(const float* __restrict__ comp, const float* __restrict__ weT,
                             const float* __restrict__ be, float* __restrict__ mnorm, int lgW)
{
    const int lgHW = 2 * lgW;
    const int HW = 1 << lgHW, W = 1 << lgW, H = W;
    int lane = threadIdx.x & 63;
    int pq = __builtin_amdgcn_readfirstlane(threadIdx.x >> 6);   // 0..3
    int pix = blockIdx.x * 64 + lane;
    int b = pix >> lgHW;
    int hw = pix & (HW - 1);
    int h = hw >> lgW, w = hw & (W - 1);

    int off[9];
    float msk[9];
    #pragma unroll
    for (int ky = 0; ky < 3; ky++) {
        int ys = h + ky - 1;
        bool yok = (unsigned)ys < (unsigned)H;
        #pragma unroll
        for (int kx = 0; kx < 3; kx++) {
            int xs = w + kx - 1;
            bool ok = yok && ((unsigned)xs < (unsigned)W);
            int kt = ky * 3 + kx;
            off[kt] = ok ? ((ys << lgW) + xs) : 0;
            msk[kt] = ok ? 1.f : 0.f;
        }
    }

    float acc[9];
    #pragma unroll
    for (int kk = 0; kk < 9; kk++) acc[kk] = be[kk * 4 + pq];

    const float* wp = weT + pq * 9216;         // [i=64][kt=9][16]
    const float* cb = comp + (((size_t)b) << lgHW) * 64;
    for (int i = 0; i < 64; i += 2) {
        // ---- load phase: 18 independent tap loads ----
        const float* ci0 = cb + ((size_t)i << lgHW);
        const float* ci1 = cb + ((size_t)(i + 1) << lgHW);
        float tap[2][9];
        #pragma unroll
        for (int kt = 0; kt < 9; kt++) tap[0][kt] = ci0[off[kt]];
        #pragma unroll
        for (int kt = 0; kt < 9; kt++) tap[1][kt] = ci1[off[kt]];
        // ---- compute phase ----
        #pragma unroll
        for (int u = 0; u < 2; u++) {
            const float* wi = wp + (i + u) * 144;
            #pragma unroll
            for (int kt = 0; kt < 9; kt++) {
                const float* wt = wi + kt * 16;
                float4 w0 = *(const float4*)(wt);
                float4 w1 = *(const float4*)(wt + 4);
                float  w8 = wt[8];
                float tv = tap[u][kt] * msk[kt];
                acc[0] += w0.x * tv; acc[1] += w0.y * tv; acc[2] += w0.z * tv;
                acc[3] += w0.w * tv; acc[4] += w1.x * tv; acc[5] += w1.y * tv;
                acc[6] += w1.z * tv; acc[7] += w1.w * tv; acc[8] += w8 * tv;
            }
        }
    }

    float m = acc[0];
    #pragma unroll
    for (int kk = 1; kk < 9; kk++) m = fmaxf(m, acc[kk]);
    float s = 0.f;
    #pragma unroll
    for (int kk = 0; kk < 9; kk++) { acc[kk] = __expf(acc[kk] - m); s += acc[kk]; }
    float r = 1.f / s;
    float* mp = mnorm + (((size_t)b * 36) << lgHW) + hw;
    #pragma unroll
    for (int kk = 0; kk < 9; kk++) mp[(size_t)(kk * 4 + pq) << lgHW] = acc[kk] * r;
}

// ---------------------------------------------------------------------------
// K3: content-aware reassembly.  36 per-pixel weights in VGPRs.  CPT=16 for
// ALL stages (4 cs block-splits: max TLP).  ch-loop unrolled x2 with 18 tap
// loads issued before the FMA phase.
// ---------------------------------------------------------------------------
template<int CPT>
__global__ LB void reassembly_k(const float* __restrict__ x, const float* __restrict__ mnorm,
                                float* __restrict__ out, int lgW)
{
    const int lgHW = 2 * lgW;
    const int HW = 1 << lgHW, W = 1 << lgW, H = W;
    int lane = threadIdx.x & 63;
    int cg = threadIdx.x >> 6;
    int nbsh = lgHW - 5;                      // pixel-blocks = npix/64 (pow2)
    int pb = blockIdx.x & ((1 << nbsh) - 1);
    int cs = blockIdx.x >> nbsh;
    int pix = pb * 64 + lane;
    int b = pix >> lgHW;
    int hw = pix & (HW - 1);
    int h = hw >> lgW, w = hw & (W - 1);

    int off[9];
    float msk[9];
    #pragma unroll
    for (int ky = 0; ky < 3; ky++) {
        int ys = h + ky - 1;
        bool yok = (unsigned)ys < (unsigned)H;
        #pragma unroll
        for (int kx = 0; kx < 3; kx++) {
            int xs = w + kx - 1;
            bool ok = yok && ((unsigned)xs < (unsigned)W);
            int kt = ky * 3 + kx;
            off[kt] = ok ? ((ys << lgW) + xs) : 0;
            msk[kt] = ok ? 1.f : 0.f;
        }
    }
    const float* mp = mnorm + (((size_t)b * 36) << lgHW) + hw;
    float wreg[36];
    #pragma unroll
    for (int ch = 0; ch < 36; ch++) wreg[ch] = mp[(size_t)ch << lgHW];

    int c0 = (cs * 4 + cg) * CPT;
    const float* xb = x + ((size_t)b * 256 + c0) * HW;
    size_t OW = (size_t)W * 2;
    float* ob = out + (((size_t)b * 256 + c0) * 2 * H + 2 * h) * OW + 2 * w;
    for (int it = 0; it < CPT; it += 2) {
        // ---- load phase: 18 independent tap loads ----
        const float* xc0 = xb + ((size_t)it << lgHW);
        const float* xc1 = xb + ((size_t)(it + 1) << lgHW);
        float tap[2][9];
        #pragma unroll
        for (int kt = 0; kt < 9; kt++) tap[0][kt] = xc0[off[kt]];
        #pragma unroll
        for (int kt = 0; kt < 9; kt++) tap[1][kt] = xc1[off[kt]];
        // ---- compute + store phase ----
        #pragma unroll
        for (int u = 0; u < 2; u++) {
            float a00 = 0.f, a01 = 0.f, a10 = 0.f, a11 = 0.f;
            #pragma unroll
            for (int kt = 0; kt < 9; kt++) {
                float tv = tap[u][kt] * msk[kt];
                a00 += tv * wreg[kt * 4 + 0];
                a01 += tv * wreg[kt * 4 + 1];
                a10 += tv * wreg[kt * 4 + 2];
                a11 += tv * wreg[kt * 4 + 3];
            }
            float* oc = ob + (size_t)(it + u) * 2 * H * OW;
            *(float2*)oc = make_float2(a00, a01);
            *(float2*)(oc + OW) = make_float2(a10, a11);
        }
    }
}

// ---------------------------------------------------------------------------
extern "C" void kernel_launch(void* const* d_in, const int* in_sizes, int n_in,
                              void* d_out, int out_size, void* d_ws, size_t ws_size,
                              hipStream_t stream)
{
    const float* src = (const float*)d_in[0];
    const float* wc[4]; const float* bc[4]; const float* we[4]; const float* be[4];
    for (int s = 0; s < 4; s++) {
        wc[s] = (const float*)d_in[2 + 4 * s];
        bc[s] = (const float*)d_in[3 + 4 * s];
        we[s] = (const float*)d_in[4 + 4 * s];
        be[s] = (const float*)d_in[5 + 4 * s];
    }
    float* ws   = (float*)d_ws;
    float* x1   = ws;                    // 2*256*32*32    =   524288
    float* x2   = x1 + 524288;           // 2*256*64*64    =  2097152
    float* x3   = x2 + 2097152;          // 2*256*128*128  =  8388608
    float* comp = x3 + 8388608;          // 2*64*128*128   =  2097152 (max, reused)
    float* mn   = comp + 2097152;        // 2*36*128*128   =  1179648 (max, reused)
    float* wcT  = mn + 1179648;          // 4*256*64    = 65536
    float* weT  = wcT + 65536;           // 4*4*64*9*16 = 147456

    prep_weights<<<dim3(81, 8), 256, 0, stream>>>(
        wc[0], wc[1], wc[2], wc[3], we[0], we[1], we[2], we[3], wcT, weT);

    const float* xin = src;
    float* stage_out[4] = {x1, x2, x3, (float*)d_out};
    int lgW = 4;
    for (int s = 0; s < 4; s++) {
        int HW = 1 << (2 * lgW);
        int npix = 2 * HW;                     // B=2
        int nb = npix >> 6;
        compress_k<<<nb, 256, 0, stream>>>(xin, wcT + s * 16384, bc[s], comp, lgW);
        encoder_k<<<nb, 256, 0, stream>>>(comp, weT + s * 36864, be[s], mn, lgW);
        reassembly_k<16><<<nb * 4, 256, 0, stream>>>(xin, mn, stage_out[s], lgW);
        xin = stage_out[s];
        lgW++;
    }
}

// Round 7
// 502.640 us; speedup vs baseline: 1.3789x; 1.3789x over previous
//
#include <hip/hip_runtime.h>

#define LB __launch_bounds__(256)

// ---------------------------------------------------------------------------
// Weight pre-transpose:
//  seg 0-3 : wc [64][256]   -> wcT  [stage][c=256][o=64]           (s3 compress)
//  seg 4-7 : we [36][64][9] -> weT  [stage][pq=4][i=64][kt=9][16]  (s3 encoder)
//  seg 8-11: we [36][64][9] -> weT3 [stage][i=64][kt=9][o=36 pad40] (s0-2 encoder)
// ---------------------------------------------------------------------------
__global__ LB void prep_weights(
    const float* __restrict__ wcA, const float* __restrict__ wcB,
    const float* __restrict__ wcC, const float* __restrict__ wcD,
    const float* __restrict__ weA, const float* __restrict__ weB,
    const float* __restrict__ weC, const float* __restrict__ weD,
    float* __restrict__ wcT, float* __restrict__ weT, float* __restrict__ weT3)
{
    int seg = blockIdx.y;
    int t = blockIdx.x * 256 + threadIdx.x;
    if (seg < 4) {
        if (t >= 64 * 256) return;
        const float* w = (seg == 0) ? wcA : (seg == 1) ? wcB : (seg == 2) ? wcC : wcD;
        int c = t & 255, o = t >> 8;
        wcT[seg * 16384 + c * 64 + o] = w[t];
    } else if (seg < 8) {
        if (t >= 36 * 64 * 9) return;
        const float* w = (seg == 4) ? weA : (seg == 5) ? weB : (seg == 6) ? weC : weD;
        int kt = t % 9;
        int r = t / 9;
        int i = r & 63;
        int o = r >> 6;
        int kk = o >> 2, pq = o & 3;
        weT[(seg - 4) * 36864 + ((pq * 64 + i) * 9 + kt) * 16 + kk] = w[t];
    } else {
        if (t >= 36 * 64 * 9) return;
        const float* w = (seg == 8) ? weA : (seg == 9) ? weB : (seg == 10) ? weC : weD;
        int kt = t % 9;
        int r = t / 9;
        int i = r & 63;
        int o = r >> 6;                        // 0..35 = kk*4+pq
        weT3[(seg - 8) * 23040 + (i * 9 + kt) * 40 + o] = w[t];
    }
}

// ---------------------------------------------------------------------------
// K1a (s0-s2): 1x1 conv 256->64, thread = (pixel, OPT outputs).
// Massive grid (npix*64/OPT threads).  Weight rows from ORIGINAL wc layout,
// wave-uniform base -> scalar loads.  8-deep x-load batches.
// ---------------------------------------------------------------------------
template<int OPT>
__global__ LB void compress_flat_k(const float* __restrict__ x, const float* __restrict__ wcO,
                                   const float* __restrict__ bc, float* __restrict__ comp,
                                   int lgW, int lgNpix)
{
    const int lgHW = 2 * lgW;
    const int HW = 1 << lgHW;
    int tid = blockIdx.x * 256 + threadIdx.x;
    int px = tid & ((1 << lgNpix) - 1);
    int og = __builtin_amdgcn_readfirstlane(tid >> lgNpix);    // uniform (npix>=64)
    int b = px >> lgHW;
    int hw = px & (HW - 1);
    const float* xp = x + (((size_t)b * 256) << lgHW) + hw;

    float acc[OPT];
    #pragma unroll
    for (int j = 0; j < OPT; j++) acc[j] = bc[og * OPT + j];

    for (int c0 = 0; c0 < 256; c0 += 8) {
        float xv[8];
        #pragma unroll
        for (int u = 0; u < 8; u++) xv[u] = xp[(size_t)(c0 + u) << lgHW];
        #pragma unroll
        for (int j = 0; j < OPT; j++) {
            const float* wr = wcO + (og * OPT + j) * 256 + c0;   // uniform row
            #pragma unroll
            for (int u = 0; u < 8; u++) acc[j] += wr[u] * xv[u];
        }
    }
    float* op = comp + (((size_t)b * 64 + og * OPT) << lgHW) + hw;
    #pragma unroll
    for (int j = 0; j < OPT; j++) op[(size_t)j << lgHW] = acc[j];
}

// ---------------------------------------------------------------------------
// K1b (s3): block-tile 1x1 conv (64 px x 4 og-waves), VALU-dense, 512 blocks.
// ---------------------------------------------------------------------------
__global__ LB void compress_k(const float* __restrict__ x, const float* __restrict__ wcT,
                              const float* __restrict__ bc, float* __restrict__ comp, int lgW)
{
    const int lgHW = 2 * lgW;
    const int HW = 1 << lgHW;
    int lane = threadIdx.x & 63;
    int og = __builtin_amdgcn_readfirstlane(threadIdx.x >> 6);
    int pix = blockIdx.x * 64 + lane;
    int b = pix >> lgHW;
    int hw = pix & (HW - 1);
    const float* xp = x + (((size_t)b * 256) << lgHW) + hw;
    const float* wr = wcT + og * 16;

    float acc[16];
    #pragma unroll
    for (int j = 0; j < 16; j++) acc[j] = bc[og * 16 + j];

    for (int c0 = 0; c0 < 256; c0 += 16) {
        float xv[16];
        #pragma unroll
        for (int u = 0; u < 16; u++)
            xv[u] = xp[(size_t)(c0 + u) << lgHW];
        #pragma unroll
        for (int u = 0; u < 16; u++) {
            const float* w = wr + (c0 + u) * 64;
            float4 w0 = *(const float4*)(w);
            float4 w1 = *(const float4*)(w + 4);
            float4 w2 = *(const float4*)(w + 8);
            float4 w3 = *(const float4*)(w + 12);
            float xu = xv[u];
            acc[0]  += w0.x * xu; acc[1]  += w0.y * xu; acc[2]  += w0.z * xu; acc[3]  += w0.w * xu;
            acc[4]  += w1.x * xu; acc[5]  += w1.y * xu; acc[6]  += w1.z * xu; acc[7]  += w1.w * xu;
            acc[8]  += w2.x * xu; acc[9]  += w2.y * xu; acc[10] += w2.z * xu; acc[11] += w2.w * xu;
            acc[12] += w3.x * xu; acc[13] += w3.y * xu; acc[14] += w3.z * xu; acc[15] += w3.w * xu;
        }
    }

    float* op = comp + (((size_t)b * 64 + og * 16) << lgHW) + hw;
    #pragma unroll
    for (int j = 0; j < 16; j++) op[(size_t)j << lgHW] = acc[j];
}

// ---------------------------------------------------------------------------
// K2a (s0-s2): wave = one pixel, lanes 0..35 = output logits o=kk*4+pq.
// Tap loads are wave-uniform broadcasts; weights coalesced over lanes.
// Softmax via 18 shfl over the kk-group (stride 4).  Blocks = npix/4.
// ---------------------------------------------------------------------------
__global__ LB void encoder_wave_k(const float* __restrict__ comp, const float* __restrict__ weT3,
                                  const float* __restrict__ be, float* __restrict__ mnorm, int lgW)
{
    const int lgHW = 2 * lgW;
    const int HW = 1 << lgHW, W = 1 << lgW, H = W;
    int lane = threadIdx.x & 63;
    int wid = threadIdx.x >> 6;
    int pix = blockIdx.x * 4 + wid;
    int b = pix >> lgHW;
    int hw = pix & (HW - 1);
    int h = hw >> lgW, w = hw & (W - 1);
    int o = lane < 36 ? lane : 35;

    int off[9];
    float msk[9];
    #pragma unroll
    for (int ky = 0; ky < 3; ky++) {
        int ys = h + ky - 1;
        bool yok = (unsigned)ys < (unsigned)H;
        #pragma unroll
        for (int kx = 0; kx < 3; kx++) {
            int xs = w + kx - 1;
            bool ok = yok && ((unsigned)xs < (unsigned)W);
            int kt = ky * 3 + kx;
            off[kt] = ok ? ((ys << lgW) + xs) : 0;
            msk[kt] = ok ? 1.f : 0.f;
        }
    }

    float acc = be[o];
    const float* cb = comp + (((size_t)b) << lgHW) * 64;
    for (int c = 0; c < 64; c += 2) {
        const float* ci0 = cb + ((size_t)c << lgHW);
        const float* ci1 = cb + ((size_t)(c + 1) << lgHW);
        float tap[2][9];
        #pragma unroll
        for (int kt = 0; kt < 9; kt++) tap[0][kt] = ci0[off[kt]];
        #pragma unroll
        for (int kt = 0; kt < 9; kt++) tap[1][kt] = ci1[off[kt]];
        const float* wr0 = weT3 + (c * 9) * 40 + o;
        #pragma unroll
        for (int u = 0; u < 2; u++) {
            #pragma unroll
            for (int kt = 0; kt < 9; kt++)
                acc += wr0[(u * 9 + kt) * 40] * (tap[u][kt] * msk[kt]);
        }
    }

    // softmax over kk (lanes o%4==pq, 9 of them)
    int pq = o & 3;
    float m = acc;
    #pragma unroll
    for (int j = 0; j < 9; j++) m = fmaxf(m, __shfl(acc, pq + j * 4, 64));
    float e = __expf(acc - m);
    float ssum = 0.f;
    #pragma unroll
    for (int j = 0; j < 9; j++) ssum += __shfl(e, pq + j * 4, 64);
    if (lane < 36)
        mnorm[((((size_t)b * 36) + o) << lgHW) + hw] = e / ssum;
}

// ---------------------------------------------------------------------------
// K2b (s3): dense encoder, thread = (pixel, pq), 2048 waves at s3.
// ---------------------------------------------------------------------------
__global__ LB void encoder_k(const float* __restrict__ comp, const float* __restrict__ weT,
                             const float* __restrict__ be, float* __restrict__ mnorm, int lgW)
{
    const int lgHW = 2 * lgW;
    const int HW = 1 << lgHW, W = 1 << lgW, H = W;
    int lane = threadIdx.x & 63;
    int pq = __builtin_amdgcn_readfirstlane(threadIdx.x >> 6);
    int pix = blockIdx.x * 64 + lane;
    int b = pix >> lgHW;
    int hw = pix & (HW - 1);
    int h = hw >> lgW, w = hw & (W - 1);

    int off[9];
    float msk[9];
    #pragma unroll
    for (int ky = 0; ky < 3; ky++) {
        int ys = h + ky - 1;
        bool yok = (unsigned)ys < (unsigned)H;
        #pragma unroll
        for (int kx = 0; kx < 3; kx++) {
            int xs = w + kx - 1;
            bool ok = yok && ((unsigned)xs < (unsigned)W);
            int kt = ky * 3 + kx;
            off[kt] = ok ? ((ys << lgW) + xs) : 0;
            msk[kt] = ok ? 1.f : 0.f;
        }
    }

    float acc[9];
    #pragma unroll
    for (int kk = 0; kk < 9; kk++) acc[kk] = be[kk * 4 + pq];

    const float* wp = weT + pq * 9216;
    const float* cb = comp + (((size_t)b) << lgHW) * 64;
    for (int i = 0; i < 64; i += 2) {
        const float* ci0 = cb + ((size_t)i << lgHW);
        const float* ci1 = cb + ((size_t)(i + 1) << lgHW);
        float tap[2][9];
        #pragma unroll
        for (int kt = 0; kt < 9; kt++) tap[0][kt] = ci0[off[kt]];
        #pragma unroll
        for (int kt = 0; kt < 9; kt++) tap[1][kt] = ci1[off[kt]];
        #pragma unroll
        for (int u = 0; u < 2; u++) {
            const float* wi = wp + (i + u) * 144;
            #pragma unroll
            for (int kt = 0; kt < 9; kt++) {
                const float* wt = wi + kt * 16;
                float4 w0 = *(const float4*)(wt);
                float4 w1 = *(const float4*)(wt + 4);
                float  w8 = wt[8];
                float tv = tap[u][kt] * msk[kt];
                acc[0] += w0.x * tv; acc[1] += w0.y * tv; acc[2] += w0.z * tv;
                acc[3] += w0.w * tv; acc[4] += w1.x * tv; acc[5] += w1.y * tv;
                acc[6] += w1.z * tv; acc[7] += w1.w * tv; acc[8] += w8 * tv;
            }
        }
    }

    float m = acc[0];
    #pragma unroll
    for (int kk = 1; kk < 9; kk++) m = fmaxf(m, acc[kk]);
    float s = 0.f;
    #pragma unroll
    for (int kk = 0; kk < 9; kk++) { acc[kk] = __expf(acc[kk] - m); s += acc[kk]; }
    float r = 1.f / s;
    float* mp = mnorm + (((size_t)b * 36) << lgHW) + hw;
    #pragma unroll
    for (int kk = 0; kk < 9; kk++) mp[(size_t)(kk * 4 + pq) << lgHW] = acc[kk] * r;
}

// ---------------------------------------------------------------------------
// K3: content-aware reassembly.  36 per-pixel weights in VGPRs; CPT channels
// per thread; 64/CPT block-splits.  CPT=8 small stages, 16 large.
// ---------------------------------------------------------------------------
template<int CPT>
__global__ LB void reassembly_k(const float* __restrict__ x, const float* __restrict__ mnorm,
                                float* __restrict__ out, int lgW)
{
    const int lgHW = 2 * lgW;
    const int HW = 1 << lgHW, W = 1 << lgW, H = W;
    int lane = threadIdx.x & 63;
    int cg = threadIdx.x >> 6;
    int nbsh = lgHW - 5;
    int pb = blockIdx.x & ((1 << nbsh) - 1);
    int cs = blockIdx.x >> nbsh;
    int pix = pb * 64 + lane;
    int b = pix >> lgHW;
    int hw = pix & (HW - 1);
    int h = hw >> lgW, w = hw & (W - 1);

    int off[9];
    float msk[9];
    #pragma unroll
    for (int ky = 0; ky < 3; ky++) {
        int ys = h + ky - 1;
        bool yok = (unsigned)ys < (unsigned)H;
        #pragma unroll
        for (int kx = 0; kx < 3; kx++) {
            int xs = w + kx - 1;
            bool ok = yok && ((unsigned)xs < (unsigned)W);
            int kt = ky * 3 + kx;
            off[kt] = ok ? ((ys << lgW) + xs) : 0;
            msk[kt] = ok ? 1.f : 0.f;
        }
    }
    const float* mp = mnorm + (((size_t)b * 36) << lgHW) + hw;
    float wreg[36];
    #pragma unroll
    for (int ch = 0; ch < 36; ch++) wreg[ch] = mp[(size_t)ch << lgHW];

    int c0 = (cs * 4 + cg) * CPT;
    const float* xb = x + ((size_t)b * 256 + c0) * HW;
    size_t OW = (size_t)W * 2;
    float* ob = out + (((size_t)b * 256 + c0) * 2 * H + 2 * h) * OW + 2 * w;
    for (int it = 0; it < CPT; it += 2) {
        const float* xc0 = xb + ((size_t)it << lgHW);
        const float* xc1 = xb + ((size_t)(it + 1) << lgHW);
        float tap[2][9];
        #pragma unroll
        for (int kt = 0; kt < 9; kt++) tap[0][kt] = xc0[off[kt]];
        #pragma unroll
        for (int kt = 0; kt < 9; kt++) tap[1][kt] = xc1[off[kt]];
        #pragma unroll
        for (int u = 0; u < 2; u++) {
            float a00 = 0.f, a01 = 0.f, a10 = 0.f, a11 = 0.f;
            #pragma unroll
            for (int kt = 0; kt < 9; kt++) {
                float tv = tap[u][kt] * msk[kt];
                a00 += tv * wreg[kt * 4 + 0];
                a01 += tv * wreg[kt * 4 + 1];
                a10 += tv * wreg[kt * 4 + 2];
                a11 += tv * wreg[kt * 4 + 3];
            }
            float* oc = ob + (size_t)(it + u) * 2 * H * OW;
            *(float2*)oc = make_float2(a00, a01);
            *(float2*)(oc + OW) = make_float2(a10, a11);
        }
    }
}

// ---------------------------------------------------------------------------
extern "C" void kernel_launch(void* const* d_in, const int* in_sizes, int n_in,
                              void* d_out, int out_size, void* d_ws, size_t ws_size,
                              hipStream_t stream)
{
    const float* src = (const float*)d_in[0];
    const float* wc[4]; const float* bc[4]; const float* we[4]; const float* be[4];
    for (int s = 0; s < 4; s++) {
        wc[s] = (const float*)d_in[2 + 4 * s];
        bc[s] = (const float*)d_in[3 + 4 * s];
        we[s] = (const float*)d_in[4 + 4 * s];
        be[s] = (const float*)d_in[5 + 4 * s];
    }
    float* ws   = (float*)d_ws;
    float* x1   = ws;                    // 2*256*32*32    =   524288
    float* x2   = x1 + 524288;           // 2*256*64*64    =  2097152
    float* x3   = x2 + 2097152;          // 2*256*128*128  =  8388608
    float* comp = x3 + 8388608;          // 2*64*128*128   =  2097152 (max, reused)
    float* mn   = comp + 2097152;        // 2*36*128*128   =  1179648 (max, reused)
    float* wcT  = mn + 1179648;          // 4*256*64     = 65536
    float* weT  = wcT + 65536;           // 4*4*64*9*16  = 147456
    float* weT3 = weT + 147456;          // 4*64*9*40    = 92160

    prep_weights<<<dim3(81, 12), 256, 0, stream>>>(
        wc[0], wc[1], wc[2], wc[3], we[0], we[1], we[2], we[3], wcT, weT, weT3);

    const float* xin = src;
    float* stage_out[4] = {x1, x2, x3, (float*)d_out};
    int lgW = 4;
    for (int s = 0; s < 4; s++) {
        int lgHW = 2 * lgW;
        int npix = 2 << lgHW;                  // B=2
        int nb = npix >> 6;
        int lgNpix = lgHW + 1;
        // K1
        if (s < 2)
            compress_flat_k<1><<<npix * 64 / 256, 256, 0, stream>>>(
                xin, wc[s], bc[s], comp, lgW, lgNpix);
        else if (s == 2)
            compress_flat_k<4><<<npix * 16 / 256, 256, 0, stream>>>(
                xin, wc[s], bc[s], comp, lgW, lgNpix);
        else
            compress_k<<<nb, 256, 0, stream>>>(xin, wcT + 3 * 16384, bc[3], comp, lgW);
        // K2
        if (s < 3)
            encoder_wave_k<<<npix / 4, 256, 0, stream>>>(
                comp, weT3 + s * 23040, be[s], mn, lgW);
        else
            encoder_k<<<nb, 256, 0, stream>>>(comp, weT + 3 * 36864, be[3], mn, lgW);
        // K3
        if (s < 2)
            reassembly_k<8><<<nb * 8, 256, 0, stream>>>(xin, mn, stage_out[s], lgW);
        else
            reassembly_k<16><<<nb * 4, 256, 0, stream>>>(xin, mn, stage_out[s], lgW);
        xin = stage_out[s];
        lgW++;
    }
}

// Round 9
// 442.775 us; speedup vs baseline: 1.5653x; 1.1352x over previous
//
#include <hip/hip_runtime.h>

#define LB __launch_bounds__(256)

// ---------------------------------------------------------------------------
// Weight pre-transpose:
//  seg 0-3 : wc [64][256]   -> wcT4 [stage][og=4][c=256][16]        (s3 compress, LDS-staged)
//  seg 4-7 : we [36][64][9] -> weT3 [stage][i=64][kt=9][o=36 pad40] (s0-2 encoder_wave)
//  seg 8-11: we [36][64][9] -> weT4 [stage][pq=4][i=64][kt=9][12]   (s3 encoder, LDS-staged)
// ---------------------------------------------------------------------------
__global__ LB void prep_weights(
    const float* __restrict__ wcA, const float* __restrict__ wcB,
    const float* __restrict__ wcC, const float* __restrict__ wcD,
    const float* __restrict__ weA, const float* __restrict__ weB,
    const float* __restrict__ weC, const float* __restrict__ weD,
    float* __restrict__ wcT4, float* __restrict__ weT3, float* __restrict__ weT4)
{
    int seg = blockIdx.y;
    int t = blockIdx.x * 256 + threadIdx.x;
    if (seg < 4) {
        if (t >= 64 * 256) return;
        const float* w = (seg == 0) ? wcA : (seg == 1) ? wcB : (seg == 2) ? wcC : wcD;
        int c = t & 255, o = t >> 8;
        wcT4[seg * 16384 + (o >> 4) * 4096 + c * 16 + (o & 15)] = w[t];
    } else if (seg < 8) {
        if (t >= 36 * 64 * 9) return;
        const float* w = (seg == 4) ? weA : (seg == 5) ? weB : (seg == 6) ? weC : weD;
        int kt = t % 9;
        int r = t / 9;
        int i = r & 63;
        int o = r >> 6;                        // 0..35 = kk*4+pq
        weT3[(seg - 4) * 23040 + (i * 9 + kt) * 40 + o] = w[t];
    } else {
        if (t >= 36 * 64 * 9) return;
        const float* w = (seg == 8) ? weA : (seg == 9) ? weB : (seg == 10) ? weC : weD;
        int kt = t % 9;
        int r = t / 9;
        int i = r & 63;
        int o = r >> 6;
        int kk = o >> 2, pq = o & 3;
        weT4[(seg - 8) * 27648 + pq * 6912 + (i * 9 + kt) * 12 + kk] = w[t];
    }
}

// ---------------------------------------------------------------------------
// K1a (s0-s2): 1x1 conv 256->64, thread = (pixel, OPT outputs), flat grid.
// ---------------------------------------------------------------------------
template<int OPT>
__global__ LB void compress_flat_k(const float* __restrict__ x, const float* __restrict__ wcO,
                                   const float* __restrict__ bc, float* __restrict__ comp,
                                   int lgW, int lgNpix)
{
    const int lgHW = 2 * lgW;
    const int HW = 1 << lgHW;
    int tid = blockIdx.x * 256 + threadIdx.x;
    int px = tid & ((1 << lgNpix) - 1);
    int og = __builtin_amdgcn_readfirstlane(tid >> lgNpix);
    int b = px >> lgHW;
    int hw = px & (HW - 1);
    const float* xp = x + (((size_t)b * 256) << lgHW) + hw;

    float acc[OPT];
    #pragma unroll
    for (int j = 0; j < OPT; j++) acc[j] = bc[og * OPT + j];

    for (int c0 = 0; c0 < 256; c0 += 8) {
        float xv[8];
        #pragma unroll
        for (int u = 0; u < 8; u++) xv[u] = xp[(size_t)(c0 + u) << lgHW];
        #pragma unroll
        for (int j = 0; j < OPT; j++) {
            const float* wr = wcO + (og * OPT + j) * 256 + c0;   // uniform row -> K$ (4KB max)
            #pragma unroll
            for (int u = 0; u < 8; u++) acc[j] += wr[u] * xv[u];
        }
    }
    float* op = comp + (((size_t)b * 64 + og * OPT) << lgHW) + hw;
    #pragma unroll
    for (int j = 0; j < OPT; j++) op[(size_t)j << lgHW] = acc[j];
}

// ---------------------------------------------------------------------------
// K1b (s3): 1x1 conv with the og-slice of weights staged in LDS (16 KB).
// blockIdx.y = og (16 outputs).  Per c: 1 coalesced x load + 4 broadcast
// ds_read_b128 -> 16 FMAs.  No scalar-cache traffic in the loop.
// ---------------------------------------------------------------------------
__global__ LB void compress_lds_k(const float* __restrict__ x, const float* __restrict__ wcT4,
                                  const float* __restrict__ bc, float* __restrict__ comp, int lgW)
{
    __shared__ float wlds[4096];               // [c=256][16]
    const int lgHW = 2 * lgW;
    const int HW = 1 << lgHW;
    int og = blockIdx.y;
    for (int t = threadIdx.x; t < 4096; t += 256)
        wlds[t] = wcT4[og * 4096 + t];
    __syncthreads();

    int px = blockIdx.x * 256 + threadIdx.x;
    int b = px >> lgHW;
    int hw = px & (HW - 1);
    const float* xp = x + (((size_t)b * 256) << lgHW) + hw;

    float acc[16];
    #pragma unroll
    for (int j = 0; j < 16; j++) acc[j] = bc[og * 16 + j];

    for (int c0 = 0; c0 < 256; c0 += 8) {
        float xv[8];
        #pragma unroll
        for (int u = 0; u < 8; u++)
            xv[u] = xp[(size_t)(c0 + u) << lgHW];
        #pragma unroll
        for (int u = 0; u < 8; u++) {
            const float* w = wlds + (c0 + u) * 16;
            float4 w0 = *(const float4*)(w);
            float4 w1 = *(const float4*)(w + 4);
            float4 w2 = *(const float4*)(w + 8);
            float4 w3 = *(const float4*)(w + 12);
            float xu = xv[u];
            acc[0]  += w0.x * xu; acc[1]  += w0.y * xu; acc[2]  += w0.z * xu; acc[3]  += w0.w * xu;
            acc[4]  += w1.x * xu; acc[5]  += w1.y * xu; acc[6]  += w1.z * xu; acc[7]  += w1.w * xu;
            acc[8]  += w2.x * xu; acc[9]  += w2.y * xu; acc[10] += w2.z * xu; acc[11] += w2.w * xu;
            acc[12] += w3.x * xu; acc[13] += w3.y * xu; acc[14] += w3.z * xu; acc[15] += w3.w * xu;
        }
    }
    float* op = comp + (((size_t)b * 64 + og * 16) << lgHW) + hw;
    #pragma unroll
    for (int j = 0; j < 16; j++) op[(size_t)j << lgHW] = acc[j];
}

// ---------------------------------------------------------------------------
// K2a (s0-s2): wave = one pixel, lanes 0..35 = output logits o=kk*4+pq.
// ---------------------------------------------------------------------------
__global__ LB void encoder_wave_k(const float* __restrict__ comp, const float* __restrict__ weT3,
                                  const float* __restrict__ be, float* __restrict__ mnorm, int lgW)
{
    const int lgHW = 2 * lgW;
    const int HW = 1 << lgHW, W = 1 << lgW, H = W;
    int lane = threadIdx.x & 63;
    int wid = threadIdx.x >> 6;
    int pix = blockIdx.x * 4 + wid;
    int b = pix >> lgHW;
    int hw = pix & (HW - 1);
    int h = hw >> lgW, w = hw & (W - 1);
    int o = lane < 36 ? lane : 35;

    int off[9];
    float msk[9];
    #pragma unroll
    for (int ky = 0; ky < 3; ky++) {
        int ys = h + ky - 1;
        bool yok = (unsigned)ys < (unsigned)H;
        #pragma unroll
        for (int kx = 0; kx < 3; kx++) {
            int xs = w + kx - 1;
            bool ok = yok && ((unsigned)xs < (unsigned)W);
            int kt = ky * 3 + kx;
            off[kt] = ok ? ((ys << lgW) + xs) : 0;
            msk[kt] = ok ? 1.f : 0.f;
        }
    }

    float acc = be[o];
    const float* cb = comp + (((size_t)b) << lgHW) * 64;
    for (int c = 0; c < 64; c += 2) {
        const float* ci0 = cb + ((size_t)c << lgHW);
        const float* ci1 = cb + ((size_t)(c + 1) << lgHW);
        float tap[2][9];
        #pragma unroll
        for (int kt = 0; kt < 9; kt++) tap[0][kt] = ci0[off[kt]];
        #pragma unroll
        for (int kt = 0; kt < 9; kt++) tap[1][kt] = ci1[off[kt]];
        const float* wr0 = weT3 + (c * 9) * 40 + o;
        #pragma unroll
        for (int u = 0; u < 2; u++) {
            #pragma unroll
            for (int kt = 0; kt < 9; kt++)
                acc += wr0[(u * 9 + kt) * 40] * (tap[u][kt] * msk[kt]);
        }
    }

    int pq = o & 3;
    float m = acc;
    #pragma unroll
    for (int j = 0; j < 9; j++) m = fmaxf(m, __shfl(acc, pq + j * 4, 64));
    float e = __expf(acc - m);
    float ssum = 0.f;
    #pragma unroll
    for (int j = 0; j < 9; j++) ssum += __shfl(e, pq + j * 4, 64);
    if (lane < 36)
        mnorm[((((size_t)b * 36) + o) << lgHW) + hw] = e / ssum;
}

// ---------------------------------------------------------------------------
// K2b (s3): encoder with this block's pq weight slice (27.6 KB) in LDS.
// blockIdx.y = pq; thread = pixel; weights read as aligned broadcast float4s.
// ---------------------------------------------------------------------------
__global__ LB void encoder_lds_k(const float* __restrict__ comp, const float* __restrict__ weT4,
                                 const float* __restrict__ be, float* __restrict__ mnorm, int lgW)
{
    __shared__ float wlds[6912];               // [i=64][kt=9][12]
    const int lgHW = 2 * lgW;
    const int HW = 1 << lgHW, W = 1 << lgW, H = W;
    int pq = blockIdx.y;
    for (int t = threadIdx.x; t < 6912; t += 256)
        wlds[t] = weT4[pq * 6912 + t];
    __syncthreads();

    int px = blockIdx.x * 256 + threadIdx.x;
    int b = px >> lgHW;
    int hw = px & (HW - 1);
    int h = hw >> lgW, w = hw & (W - 1);

    int off[9];
    float msk[9];
    #pragma unroll
    for (int ky = 0; ky < 3; ky++) {
        int ys = h + ky - 1;
        bool yok = (unsigned)ys < (unsigned)H;
        #pragma unroll
        for (int kx = 0; kx < 3; kx++) {
            int xs = w + kx - 1;
            bool ok = yok && ((unsigned)xs < (unsigned)W);
            int kt = ky * 3 + kx;
            off[kt] = ok ? ((ys << lgW) + xs) : 0;
            msk[kt] = ok ? 1.f : 0.f;
        }
    }

    float acc[9];
    #pragma unroll
    for (int kk = 0; kk < 9; kk++) acc[kk] = be[kk * 4 + pq];

    const float* cb = comp + (((size_t)b) << lgHW) * 64;
    for (int i = 0; i < 64; i += 2) {
        const float* ci0 = cb + ((size_t)i << lgHW);
        const float* ci1 = cb + ((size_t)(i + 1) << lgHW);
        float tap[2][9];
        #pragma unroll
        for (int kt = 0; kt < 9; kt++) tap[0][kt] = ci0[off[kt]];
        #pragma unroll
        for (int kt = 0; kt < 9; kt++) tap[1][kt] = ci1[off[kt]];
        #pragma unroll
        for (int u = 0; u < 2; u++) {
            const float* wi = wlds + (i + u) * 108;
            #pragma unroll
            for (int kt = 0; kt < 9; kt++) {
                const float* wt = wi + kt * 12;
                float4 w0 = *(const float4*)(wt);
                float4 w1 = *(const float4*)(wt + 4);
                float  w8 = wt[8];
                float tv = tap[u][kt] * msk[kt];
                acc[0] += w0.x * tv; acc[1] += w0.y * tv; acc[2] += w0.z * tv;
                acc[3] += w0.w * tv; acc[4] += w1.x * tv; acc[5] += w1.y * tv;
                acc[6] += w1.z * tv; acc[7] += w1.w * tv; acc[8] += w8 * tv;
            }
        }
    }

    float m = acc[0];
    #pragma unroll
    for (int kk = 1; kk < 9; kk++) m = fmaxf(m, acc[kk]);
    float s = 0.f;
    #pragma unroll
    for (int kk = 0; kk < 9; kk++) { acc[kk] = __expf(acc[kk] - m); s += acc[kk]; }
    float r = 1.f / s;
    float* mp = mnorm + (((size_t)b * 36) << lgHW) + hw;
    #pragma unroll
    for (int kk = 0; kk < 9; kk++) mp[(size_t)(kk * 4 + pq) << lgHW] = acc[kk] * r;
}

// ---------------------------------------------------------------------------
// K3: content-aware reassembly.  36 per-pixel weights in VGPRs; CPT channels
// per thread; 64/(4*CPT) cs block-splits.
// ---------------------------------------------------------------------------
template<int CPT>
__global__ LB void reassembly_k(const float* __restrict__ x, const float* __restrict__ mnorm,
                                float* __restrict__ out, int lgW)
{
    const int lgHW = 2 * lgW;
    const int HW = 1 << lgHW, W = 1 << lgW, H = W;
    int lane = threadIdx.x & 63;
    int cg = threadIdx.x >> 6;
    int nbsh = lgHW - 5;
    int pb = blockIdx.x & ((1 << nbsh) - 1);
    int cs = blockIdx.x >> nbsh;
    int pix = pb * 64 + lane;
    int b = pix >> lgHW;
    int hw = pix & (HW - 1);
    int h = hw >> lgW, w = hw & (W - 1);

    int off[9];
    float msk[9];
    #pragma unroll
    for (int ky = 0; ky < 3; ky++) {
        int ys = h + ky - 1;
        bool yok = (unsigned)ys < (unsigned)H;
        #pragma unroll
        for (int kx = 0; kx < 3; kx++) {
            int xs = w + kx - 1;
            bool ok = yok && ((unsigned)xs < (unsigned)W);
            int kt = ky * 3 + kx;
            off[kt] = ok ? ((ys << lgW) + xs) : 0;
            msk[kt] = ok ? 1.f : 0.f;
        }
    }
    const float* mp = mnorm + (((size_t)b * 36) << lgHW) + hw;
    float wreg[36];
    #pragma unroll
    for (int ch = 0; ch < 36; ch++) wreg[ch] = mp[(size_t)ch << lgHW];

    int c0 = (cs * 4 + cg) * CPT;
    const float* xb = x + ((size_t)b * 256 + c0) * HW;
    size_t OW = (size_t)W * 2;
    float* ob = out + (((size_t)b * 256 + c0) * 2 * H + 2 * h) * OW + 2 * w;
    for (int it = 0; it < CPT; it += 2) {
        const float* xc0 = xb + ((size_t)it << lgHW);
        const float* xc1 = xb + ((size_t)(it + 1) << lgHW);
        float tap[2][9];
        #pragma unroll
        for (int kt = 0; kt < 9; kt++) tap[0][kt] = xc0[off[kt]];
        #pragma unroll
        for (int kt = 0; kt < 9; kt++) tap[1][kt] = xc1[off[kt]];
        #pragma unroll
        for (int u = 0; u < 2; u++) {
            float a00 = 0.f, a01 = 0.f, a10 = 0.f, a11 = 0.f;
            #pragma unroll
            for (int kt = 0; kt < 9; kt++) {
                float tv = tap[u][kt] * msk[kt];
                a00 += tv * wreg[kt * 4 + 0];
                a01 += tv * wreg[kt * 4 + 1];
                a10 += tv * wreg[kt * 4 + 2];
                a11 += tv * wreg[kt * 4 + 3];
            }
            float* oc = ob + (size_t)(it + u) * 2 * H * OW;
            *(float2*)oc = make_float2(a00, a01);
            *(float2*)(oc + OW) = make_float2(a10, a11);
        }
    }
}

// ---------------------------------------------------------------------------
extern "C" void kernel_launch(void* const* d_in, const int* in_sizes, int n_in,
                              void* d_out, int out_size, void* d_ws, size_t ws_size,
                              hipStream_t stream)
{
    const float* src = (const float*)d_in[0];
    const float* wc[4]; const float* bc[4]; const float* we[4]; const float* be[4];
    for (int s = 0; s < 4; s++) {
        wc[s] = (const float*)d_in[2 + 4 * s];
        bc[s] = (const float*)d_in[3 + 4 * s];
        we[s] = (const float*)d_in[4 + 4 * s];
        be[s] = (const float*)d_in[5 + 4 * s];
    }
    float* ws   = (float*)d_ws;
    float* x1   = ws;                    // 2*256*32*32    =   524288
    float* x2   = x1 + 524288;           // 2*256*64*64    =  2097152
    float* x3   = x2 + 2097152;          // 2*256*128*128  =  8388608
    float* comp = x3 + 8388608;          // 2*64*128*128   =  2097152 (max, reused)
    float* mn   = comp + 2097152;        // 2*36*128*128   =  1179648 (max, reused)
    float* wcT4 = mn + 1179648;          // 4*4*256*16   = 65536
    float* weT3 = wcT4 + 65536;          // 4*64*9*40    = 92160
    float* weT4 = weT3 + 92160;          // 4*4*64*9*12  = 110592

    prep_weights<<<dim3(81, 12), 256, 0, stream>>>(
        wc[0], wc[1], wc[2], wc[3], we[0], we[1], we[2], we[3], wcT4, weT3, weT4);

    const float* xin = src;
    float* stage_out[4] = {x1, x2, x3, (float*)d_out};
    int lgW = 4;
    for (int s = 0; s < 4; s++) {
        int lgHW = 2 * lgW;
        int npix = 2 << lgHW;                  // B=2
        int nb = npix >> 6;
        int lgNpix = lgHW + 1;
        // K1
        if (s < 2)
            compress_flat_k<1><<<npix * 64 / 256, 256, 0, stream>>>(
                xin, wc[s], bc[s], comp, lgW, lgNpix);
        else if (s == 2)
            compress_flat_k<4><<<npix * 16 / 256, 256, 0, stream>>>(
                xin, wc[s], bc[s], comp, lgW, lgNpix);
        else
            compress_lds_k<<<dim3(npix / 256, 4), 256, 0, stream>>>(
                xin, wcT4 + 3 * 16384, bc[3], comp, lgW);
        // K2
        if (s < 3)
            encoder_wave_k<<<npix / 4, 256, 0, stream>>>(
                comp, weT3 + s * 23040, be[s], mn, lgW);
        else
            encoder_lds_k<<<dim3(npix / 256, 4), 256, 0, stream>>>(
                comp, weT4 + 3 * 27648, be[3], mn, lgW);
        // K3
        if (s == 0)
            reassembly_k<4><<<nb * 16, 256, 0, stream>>>(xin, mn, stage_out[s], lgW);
        else if (s == 1)
            reassembly_k<8><<<nb * 8, 256, 0, stream>>>(xin, mn, stage_out[s], lgW);
        else if (s == 2)
            reassembly_k<16><<<nb * 4, 256, 0, stream>>>(xin, mn, stage_out[s], lgW);
        else
            reassembly_k<32><<<nb * 2, 256, 0, stream>>>(xin, mn, stage_out[s], lgW);
        xin = stage_out[s];
        lgW++;
    }
}